// Round 10
// baseline (381.632 us; speedup 1.0000x reference)
//
#include <hip/hip_runtime.h>
#include <math.h>

#define H 64
#define FIN 39
#define NG 8
#define PB 1024  // partition blocks

typedef _Float16 half8 __attribute__((ext_vector_type(8)));
typedef _Float16 half4 __attribute__((ext_vector_type(4)));
typedef float floatx4 __attribute__((ext_vector_type(4)));

// ---- phase 1: per-(block,group) histogram of destination groups ----
__global__ void k_hist(const int* __restrict__ col, int* __restrict__ h,
                       int E, int R, int chunk) {
    __shared__ int hc[NG];
    int b = blockIdx.x;
    if (threadIdx.x < NG) hc[threadIdx.x] = 0;
    __syncthreads();
    int lo = b * chunk, hi = min(E, lo + chunk);
    for (int e = lo + threadIdx.x; e < hi; e += 256) {
        int c = col[e];
        atomicAdd(&hc[c / R], 1);
    }
    __syncthreads();
    if (threadIdx.x < NG) h[threadIdx.x * PB + b] = hc[threadIdx.x];
}

// ---- phase 2: scan histogram -> per-(group,block) base, group ranges ----
__global__ void k_hscan(const int* __restrict__ h, int* __restrict__ base,
                        int* __restrict__ gstart) {
    __shared__ int lds[PB];
    __shared__ int tot;
    int tid = threadIdx.x;
    int run = 0;
    for (int g = 0; g < NG; ++g) {
        int v = h[g * PB + tid];
        lds[tid] = v;
        __syncthreads();
        int acc = v;
        for (int off = 1; off < PB; off <<= 1) {
            int t = (tid >= off) ? lds[tid - off] : 0;
            __syncthreads();
            acc += t;
            lds[tid] = acc;
            __syncthreads();
        }
        if (tid == 0) gstart[g] = run;
        base[g * PB + tid] = run + acc - v;
        if (tid == PB - 1) tot = acc;
        __syncthreads();
        run += tot;
        __syncthreads();
    }
    if (tid == 0) gstart[NG] = run;
}

// ---- phase 3: scatter edges into group-partitioned compact pair array ----
__global__ void k_part(const int* __restrict__ row, const int* __restrict__ col,
                       const int* __restrict__ base, int2* __restrict__ pairs,
                       int E, int R, int chunk) {
    __shared__ int cur[NG];
    int b = blockIdx.x;
    if (threadIdx.x < NG) cur[threadIdx.x] = base[threadIdx.x * PB + b];
    __syncthreads();
    int lo = b * chunk, hi = min(E, lo + chunk);
    for (int e = lo + threadIdx.x; e < hi; e += 256) {
        int c = col[e];
        int r = row[e];
        int pos = atomicAdd(&cur[c / R], 1);
        pairs[pos] = make_int2(c, r);
    }
}

// ---- in-degree from partitioned pairs (group-local L2 traffic) ----
__global__ void k_deg2(const int2* __restrict__ pairs, const int* __restrict__ gstart,
                       int* __restrict__ deg) {
    int g = blockIdx.x & 7, bg = blockIdx.x >> 3, nbg = gridDim.x >> 3;
    int lo = gstart[g], hi = gstart[g + 1];
    for (int i = lo + bg * 256 + threadIdx.x; i < hi; i += nbg * 256)
        atomicAdd(&deg[pairs[i].x], 1);
}

// ---- scan step 1 ----
__global__ void k_scan1(const int* __restrict__ deg, int* __restrict__ startv,
                        int* __restrict__ bsum, float* __restrict__ cnt, int N) {
    __shared__ int lds[256];
    int tid = threadIdx.x;
    int i = blockIdx.x * 256 + tid;
    int v = (i < N) ? deg[i] : 0;
    if (i < N) cnt[i] = (float)v;
    lds[tid] = v;
    __syncthreads();
    int acc = v;
    for (int off = 1; off < 256; off <<= 1) {
        int t = (tid >= off) ? lds[tid - off] : 0;
        __syncthreads();
        acc += t;
        lds[tid] = acc;
        __syncthreads();
    }
    if (i < N) startv[i] = acc - v;
    if (tid == 255) bsum[blockIdx.x] = acc;
}

// ---- scan step 2 (nb <= 512) ----
__global__ void k_scan2(int* __restrict__ bsum, int nb) {
    __shared__ int lds[512];
    int tid = threadIdx.x;
    int v = (tid < nb) ? bsum[tid] : 0;
    lds[tid] = v;
    __syncthreads();
    int acc = v;
    for (int off = 1; off < 512; off <<= 1) {
        int t = (tid >= off) ? lds[tid - off] : 0;
        __syncthreads();
        acc += t;
        lds[tid] = acc;
        __syncthreads();
    }
    if (tid < nb) bsum[tid] = acc - v;
}

// ---- scan step 3 ----
__global__ void k_scan3(int* __restrict__ startv, const int* __restrict__ bsum,
                        int* __restrict__ cursor, int N) {
    int i = blockIdx.x * 256 + threadIdx.x;
    if (i < N) {
        int s = startv[i] + bsum[blockIdx.x];
        startv[i] = s;
        cursor[i] = s;
    }
}

// ---- fill CSR from partitioned pairs (group-local) ----
__global__ void k_fill2(const int2* __restrict__ pairs, const int* __restrict__ gstart,
                        int* __restrict__ cursor, int* __restrict__ csr) {
    int g = blockIdx.x & 7, bg = blockIdx.x >> 3, nbg = gridDim.x >> 3;
    int lo = gstart[g], hi = gstart[g + 1];
    for (int i = lo + bg * 256 + threadIdx.x; i < hi; i += nbg * 256) {
        int2 p = pairs[i];
        int pos = atomicAdd(&cursor[p.x], 1);
        csr[pos] = p.y;
    }
}

// ---- pack W [128][64] fp32 -> MFMA B-fragments fp16 ----
__global__ void k_packW(const float* __restrict__ msgW, const float* __restrict__ updW,
                        _Float16* __restrict__ wpk) {
    int mat = blockIdx.x;
    const float* W = (mat < 2) ? (msgW + (size_t)mat * 2 * H * H)
                               : (updW + (size_t)(mat - 2) * 2 * H * H);
    _Float16* dst = wpk + (size_t)mat * 16 * 64 * 8;
    for (int e = threadIdx.x; e < 16 * 64; e += 256) {
        int fidx = e >> 6;
        int l = e & 63;
        int hf = fidx >> 3;
        int s = (fidx >> 2) & 1;
        int t = fidx & 3;
        int kbase = hf * 64 + s * 32 + ((l >> 4) * 8);
        int c = t * 16 + (l & 15);
        _Float16* d = dst + (size_t)e * 8;
        #pragma unroll
        for (int i = 0; i < 8; ++i)
            d[i] = (_Float16)W[(size_t)(kbase + i) * H + c];
    }
}

// ---- h16 = fp16(x @ W_in + b_in) ----
__global__ void k_input(const float* __restrict__ x, const float* __restrict__ Win,
                        const float* __restrict__ bin, _Float16* __restrict__ h16, int N) {
    __shared__ float w[FIN * H];
    int tid = threadIdx.x;
    for (int i = tid; i < FIN * H; i += 512) w[i] = Win[i];
    __syncthreads();
    int j = tid & 63;
    int un = __builtin_amdgcn_readfirstlane(blockIdx.x * 32 + (tid >> 6) * 4);
    int n0 = min(un, N - 1), n1 = min(un + 1, N - 1), n2 = min(un + 2, N - 1), n3 = min(un + 3, N - 1);
    const float* x0 = x + (size_t)n0 * FIN;
    const float* x1 = x + (size_t)n1 * FIN;
    const float* x2 = x + (size_t)n2 * FIN;
    const float* x3 = x + (size_t)n3 * FIN;
    float a0 = 0.f, a1 = 0.f, a2 = 0.f, a3 = 0.f;
    #pragma unroll
    for (int k = 0; k < FIN; ++k) {
        float wv = w[k * H + j];
        a0 += x0[k] * wv;
        a1 += x1[k] * wv;
        a2 += x2[k] * wv;
        a3 += x3[k] * wv;
    }
    float bj = bin[j];
    if (un     < N) h16[(size_t)n0 * H + j] = (_Float16)(a0 + bj);
    if (un + 1 < N) h16[(size_t)n1 * H + j] = (_Float16)(a1 + bj);
    if (un + 2 < N) h16[(size_t)n2 * H + j] = (_Float16)(a2 + bj);
    if (un + 3 < N) h16[(size_t)n3 * H + j] = (_Float16)(a3 + bj);
}

// ---- MFMA: A(fp16) = h@W_top ; aggr_init = cnt*(h@W_bot + msg_b) ----
__global__ __launch_bounds__(256) void k_AB(const _Float16* __restrict__ h16,
        const _Float16* __restrict__ wpk, const float* __restrict__ bias,
        const float* __restrict__ cnt, _Float16* __restrict__ A,
        float* __restrict__ ag, int N) {
    int l = threadIdx.x & 63;
    int w = threadIdx.x >> 6;
    int n0 = blockIdx.x * 64 + w * 16;
    int mrow = l & 15, kgrp = l >> 4;
    int nA = min(n0 + mrow, N - 1);
    half8 ah0 = *(const half8*)(h16 + (size_t)nA * H + kgrp * 8);
    half8 ah1 = *(const half8*)(h16 + (size_t)nA * H + 32 + kgrp * 8);
    floatx4 accA[4] = {};
    floatx4 accB[4] = {};
    #pragma unroll
    for (int s = 0; s < 2; ++s) {
        half8 a = s ? ah1 : ah0;
        #pragma unroll
        for (int t = 0; t < 4; ++t) {
            half8 bt = *(const half8*)(wpk + ((size_t)((s * 4 + t) * 64 + l)) * 8);
            half8 bb = *(const half8*)(wpk + ((size_t)((8 + s * 4 + t) * 64 + l)) * 8);
            accA[t] = __builtin_amdgcn_mfma_f32_16x16x32_f16(a, bt, accA[t], 0, 0, 0);
            accB[t] = __builtin_amdgcn_mfma_f32_16x16x32_f16(a, bb, accB[t], 0, 0, 0);
        }
    }
    float bl[4];
    #pragma unroll
    for (int t = 0; t < 4; ++t) bl[t] = bias[t * 16 + mrow];
    #pragma unroll
    for (int r = 0; r < 4; ++r) {
        int n = n0 + kgrp * 4 + r;
        if (n < N) {
            float c = cnt[n];
            #pragma unroll
            for (int t = 0; t < 4; ++t) {
                int j = t * 16 + mrow;
                A[(size_t)n * H + j] = (_Float16)accA[t][r];
                ag[(size_t)n * H + j] = c * (accB[t][r] + bl[t]);
            }
        }
    }
}

// ---- aggr gather: 4 edges per wave-instruction, half4 row slices ----
__global__ void k_aggr(const int* __restrict__ startv, const int* __restrict__ deg,
                       const int* __restrict__ csr, const _Float16* __restrict__ A,
                       float* __restrict__ ag, int N) {
    int tid = threadIdx.x;
    int n = __builtin_amdgcn_readfirstlane(blockIdx.x * 4 + (tid >> 6));
    if (n >= N) return;
    int l = tid & 63;
    int q = l >> 4;
    int m = l & 15;
    int s = startv[n];
    int d = deg[n];
    float a0 = 0.f, a1 = 0.f, a2 = 0.f, a3 = 0.f;
    int i = 0;
    for (; i + 8 <= d; i += 8) {
        int rA = csr[s + i + q];
        int rB = csr[s + i + 4 + q];
        half4 hA = *(const half4*)(A + (size_t)rA * H + m * 4);
        half4 hB = *(const half4*)(A + (size_t)rB * H + m * 4);
        a0 += (float)hA[0] + (float)hB[0];
        a1 += (float)hA[1] + (float)hB[1];
        a2 += (float)hA[2] + (float)hB[2];
        a3 += (float)hA[3] + (float)hB[3];
    }
    for (; i < d; i += 4) {
        int ii = i + q;
        if (ii < d) {
            int r = csr[s + ii];
            half4 hv = *(const half4*)(A + (size_t)r * H + m * 4);
            a0 += (float)hv[0];
            a1 += (float)hv[1];
            a2 += (float)hv[2];
            a3 += (float)hv[3];
        }
    }
    a0 += __shfl_xor(a0, 16); a0 += __shfl_xor(a0, 32);
    a1 += __shfl_xor(a1, 16); a1 += __shfl_xor(a1, 32);
    a2 += __shfl_xor(a2, 16); a2 += __shfl_xor(a2, 32);
    a3 += __shfl_xor(a3, 16); a3 += __shfl_xor(a3, 32);
    if (q == 0) {
        float* p = ag + (size_t)n * H + m * 4;
        float4 base = *(const float4*)p;
        base.x += a0; base.y += a1; base.z += a2; base.w += a3;
        *(float4*)p = base;
    }
}

// ---- MFMA upd + LN (+ fused out MLP) ----
template<bool DO_OUT>
__global__ __launch_bounds__(256) void k_upd(const _Float16* __restrict__ h16in,
        const float* __restrict__ ag, const float* __restrict__ cnt,
        const _Float16* __restrict__ wpk, const float* __restrict__ bias,
        const float* __restrict__ lng, const float* __restrict__ lnb,
        _Float16* __restrict__ h16out,
        const float* __restrict__ W1, const float* __restrict__ b1,
        const float* __restrict__ W2, const float* __restrict__ b2,
        float* __restrict__ out, int N) {
    __shared__ float w1s[DO_OUT ? H * 32 : 1];
    __shared__ float hsmem[DO_OUT ? 4 * 16 * H : 1];
    if (DO_OUT) {
        for (int i = threadIdx.x; i < H * 32; i += 256) w1s[i] = W1[i];
    }
    int l = threadIdx.x & 63;
    int w = threadIdx.x >> 6;
    int n0 = blockIdx.x * 64 + w * 16;
    int mrow = l & 15, kgrp = l >> 4;
    int nA = min(n0 + mrow, N - 1);
    half8 ah0 = *(const half8*)(h16in + (size_t)nA * H + kgrp * 8);
    half8 ah1 = *(const half8*)(h16in + (size_t)nA * H + 32 + kgrp * 8);
    float rd = 1.0f / fmaxf(cnt[nA], 1.0f);
    half8 agf[2];
    #pragma unroll
    for (int s = 0; s < 2; ++s) {
        const float* gp = ag + (size_t)nA * H + s * 32 + kgrp * 8;
        float4 g0 = *(const float4*)gp;
        float4 g1 = *(const float4*)(gp + 4);
        half8 v;
        v[0] = (_Float16)(g0.x * rd); v[1] = (_Float16)(g0.y * rd);
        v[2] = (_Float16)(g0.z * rd); v[3] = (_Float16)(g0.w * rd);
        v[4] = (_Float16)(g1.x * rd); v[5] = (_Float16)(g1.y * rd);
        v[6] = (_Float16)(g1.z * rd); v[7] = (_Float16)(g1.w * rd);
        agf[s] = v;
    }
    floatx4 acc[4] = {};
    #pragma unroll
    for (int s = 0; s < 2; ++s) {
        half8 a = s ? ah1 : ah0;
        half8 gfr = agf[s];
        #pragma unroll
        for (int t = 0; t < 4; ++t) {
            half8 bt = *(const half8*)(wpk + ((size_t)((s * 4 + t) * 64 + l)) * 8);
            half8 bb = *(const half8*)(wpk + ((size_t)((8 + s * 4 + t) * 64 + l)) * 8);
            acc[t] = __builtin_amdgcn_mfma_f32_16x16x32_f16(a, bt, acc[t], 0, 0, 0);
            acc[t] = __builtin_amdgcn_mfma_f32_16x16x32_f16(gfr, bb, acc[t], 0, 0, 0);
        }
    }
    float bl[4], gl[4], bb2[4];
    #pragma unroll
    for (int t = 0; t < 4; ++t) {
        int j = t * 16 + mrow;
        bl[t] = bias[j]; gl[t] = lng[j]; bb2[t] = lnb[j];
    }
    float zt[4][4];
    #pragma unroll
    for (int r = 0; r < 4; ++r) {
        int n = min(n0 + kgrp * 4 + r, N - 1);
        #pragma unroll
        for (int t = 0; t < 4; ++t) {
            float hv = (float)h16in[(size_t)n * H + t * 16 + mrow];
            zt[t][r] = hv + acc[t][r] + bl[t];
        }
    }
    #pragma unroll
    for (int r = 0; r < 4; ++r) {
        float s = zt[0][r] + zt[1][r] + zt[2][r] + zt[3][r];
        s += __shfl_xor(s, 1); s += __shfl_xor(s, 2);
        s += __shfl_xor(s, 4); s += __shfl_xor(s, 8);
        float mu = s * (1.0f / H);
        float v = 0.f;
        #pragma unroll
        for (int t = 0; t < 4; ++t) { float d = zt[t][r] - mu; v += d * d; }
        v += __shfl_xor(v, 1); v += __shfl_xor(v, 2);
        v += __shfl_xor(v, 4); v += __shfl_xor(v, 8);
        float rinv = rsqrtf(v * (1.0f / H) + 1e-5f);
        int m = kgrp * 4 + r;
        int n = n0 + m;
        #pragma unroll
        for (int t = 0; t < 4; ++t) {
            float hval = (zt[t][r] - mu) * rinv * gl[t] + bb2[t];
            if (DO_OUT) hsmem[(w * 16 + m) * H + t * 16 + mrow] = hval;
            else if (n < N) h16out[(size_t)n * H + t * 16 + mrow] = (_Float16)hval;
        }
    }
    if (DO_OUT) {
        __syncthreads();
        int hf = l >> 5, jj = l & 31;
        float w2v = W2[jj];
        float b1v = b1[jj];
        float b2v = b2[0];
        for (int nn = 0; nn < 16; ++nn) {
            int n = n0 + nn;
            if (n >= N) continue;
            const float* hrow = &hsmem[(w * 16 + nn) * H];
            float t = 0.f;
            #pragma unroll
            for (int kk = 0; kk < 32; ++kk)
                t += hrow[hf * 32 + kk] * w1s[(hf * 32 + kk) * 32 + jj];
            t += __shfl_xor(t, 32);
            float t2 = t + b1v;
            float ge = 0.5f * t2 * (1.0f + erff(t2 * 0.70710678118654752f)) * w2v;
            ge += __shfl_xor(ge, 16); ge += __shfl_xor(ge, 8);
            ge += __shfl_xor(ge, 4);  ge += __shfl_xor(ge, 2);
            ge += __shfl_xor(ge, 1);
            if (l == 0) out[n] = 1.0f / (1.0f + expf(-(ge + b2v)));
        }
    }
}

extern "C" void kernel_launch(void* const* d_in, const int* in_sizes, int n_in,
                              void* d_out, int out_size, void* d_ws, size_t ws_size,
                              hipStream_t stream) {
    const float* x    = (const float*)d_in[0];
    const int*   ei   = (const int*)d_in[1];
    const float* Win  = (const float*)d_in[2];
    const float* bin  = (const float*)d_in[3];
    const float* msgW = (const float*)d_in[4];
    const float* msgb = (const float*)d_in[5];
    const float* updW = (const float*)d_in[6];
    const float* updb = (const float*)d_in[7];
    const float* lng  = (const float*)d_in[8];
    const float* lnb  = (const float*)d_in[9];
    const float* W1   = (const float*)d_in[10];
    const float* b1   = (const float*)d_in[11];
    const float* W2   = (const float*)d_in[12];
    const float* b2   = (const float*)d_in[13];

    int N = in_sizes[0] / FIN;
    int E = in_sizes[1] / 2;
    const int* row = ei;
    const int* col = ei + E;

    float* wsp  = (float*)d_ws;
    float* cnt  = wsp;                          // N f32
    float* Z    = wsp + N;                      // N*H f32 (aggr)
    _Float16* Ah   = (_Float16*)(Z + (size_t)N * H);   // N*H f16 (messages)
    _Float16* h16a = Ah + (size_t)N * H;        // N*H f16
    _Float16* h16b = h16a + (size_t)N * H;      // N*H f16
    _Float16* wpk  = h16b + (size_t)N * H;      // 4*16*64*8 f16 = 64KB
    int* deg    = (int*)(wpk + 4 * 16 * 64 * 8);// N
    int* startv = deg + N;                      // N
    int* cursor = startv + N;                   // N
    int* bsum   = cursor + N;                   // 512
    int* hh     = bsum + 512;                   // NG*PB
    int* base   = hh + NG * PB;                 // NG*PB
    int* gstart = base + NG * PB;               // 16
    int* csr    = gstart + 16;                  // E
    int2* pairs = (int2*)(csr + E);             // E int2

    int nb = (N + 255) / 256;
    int nb64 = (N + 63) / 64;
    int R = (N + NG - 1) / NG;
    int chunk = (E + PB - 1) / PB;

    hipMemsetAsync(deg, 0, (size_t)N * sizeof(int), stream);
    k_packW<<<4, 256, 0, stream>>>(msgW, updW, wpk);

    // single-pass radix partition of edges by destination group
    k_hist<<<PB, 256, 0, stream>>>(col, hh, E, R, chunk);
    k_hscan<<<1, PB, 0, stream>>>(hh, base, gstart);
    k_part<<<PB, 256, 0, stream>>>(row, col, base, pairs, E, R, chunk);

    // CSR build on group-local compact slices
    k_deg2<<<2048, 256, 0, stream>>>(pairs, gstart, deg);
    k_scan1<<<nb, 256, 0, stream>>>(deg, startv, bsum, cnt, N);
    k_scan2<<<1, 512, 0, stream>>>(bsum, nb);
    k_scan3<<<nb, 256, 0, stream>>>(startv, bsum, cursor, N);
    k_fill2<<<2048, 256, 0, stream>>>(pairs, gstart, cursor, csr);

    k_input<<<(N + 31) / 32, 512, 0, stream>>>(x, Win, bin, h16a, N);

    // layer 0: h=h16a -> A->Ah, aggr->Z, hout->h16b
    k_AB<<<nb64, 256, 0, stream>>>(h16a, wpk + 0 * 8192, msgb, cnt, Ah, Z, N);
    k_aggr<<<(N + 3) / 4, 256, 0, stream>>>(startv, deg, csr, Ah, Z, N);
    k_upd<false><<<nb64, 256, 0, stream>>>(h16a, Z, cnt, wpk + 2 * 8192, updb, lng, lnb,
                                           h16b, nullptr, nullptr, nullptr, nullptr,
                                           nullptr, N);

    // layer 1: h=h16b -> A->Ah, aggr->Z, fused final MLP -> d_out
    k_AB<<<nb64, 256, 0, stream>>>(h16b, wpk + 1 * 8192, msgb + H, cnt, Ah, Z, N);
    k_aggr<<<(N + 3) / 4, 256, 0, stream>>>(startv, deg, csr, Ah, Z, N);
    k_upd<true><<<nb64, 256, 0, stream>>>(h16b, Z, cnt, wpk + 3 * 8192, updb + H,
                                          lng + H, lnb + H, nullptr,
                                          W1, b1, W2, b2, (float*)d_out, N);
}

// Round 11
// 260.989 us; speedup vs baseline: 1.4623x; 1.4623x over previous
//
#include <hip/hip_runtime.h>
#include <math.h>
#include <stdint.h>

#define H 64
#define FIN 39
#define PB 512        // partition blocks
#define NRSH 9        // nodes per bucket = 512 (shift)
#define NBUK_MAX 256

typedef _Float16 half8 __attribute__((ext_vector_type(8)));
typedef _Float16 half4 __attribute__((ext_vector_type(4)));
typedef float floatx4 __attribute__((ext_vector_type(4)));

// ---- phase 1: per-(bucket,block) histogram ----
__global__ void k_hist(const int* __restrict__ col, int* __restrict__ hist,
                       int E, int nbuk, int chunk) {
    __shared__ int hc[NBUK_MAX];
    int b = blockIdx.x;
    for (int i = threadIdx.x; i < nbuk; i += 256) hc[i] = 0;
    __syncthreads();
    int lo = b * chunk, hi = min(E, lo + chunk);
    for (int e = lo + threadIdx.x; e < hi; e += 256)
        atomicAdd(&hc[col[e] >> NRSH], 1);
    __syncthreads();
    for (int i = threadIdx.x; i < nbuk; i += 256) hist[i * PB + b] = hc[i];
}

// ---- generic scan: per-block scan + bsum ----
__global__ void k_scanA(const int* __restrict__ in, int* __restrict__ out,
                        int* __restrict__ bsum, int M) {
    __shared__ int lds[256];
    int tid = threadIdx.x;
    int i = blockIdx.x * 256 + tid;
    int v = (i < M) ? in[i] : 0;
    lds[tid] = v;
    __syncthreads();
    int acc = v;
    for (int off = 1; off < 256; off <<= 1) {
        int t = (tid >= off) ? lds[tid - off] : 0;
        __syncthreads();
        acc += t;
        lds[tid] = acc;
        __syncthreads();
    }
    if (i < M) out[i] = acc - v;
    if (tid == 255) bsum[blockIdx.x] = acc;
}

// ---- scan of block sums (nb <= 512) ----
__global__ void k_scan2(int* __restrict__ bsum, int nb) {
    __shared__ int lds[512];
    int tid = threadIdx.x;
    int v = (tid < nb) ? bsum[tid] : 0;
    lds[tid] = v;
    __syncthreads();
    int acc = v;
    for (int off = 1; off < 512; off <<= 1) {
        int t = (tid >= off) ? lds[tid - off] : 0;
        __syncthreads();
        acc += t;
        lds[tid] = acc;
        __syncthreads();
    }
    if (tid < nb) bsum[tid] = acc - v;
}

// ---- add block offsets ----
__global__ void k_scanC(int* __restrict__ out, const int* __restrict__ bsum, int M) {
    int i = blockIdx.x * 256 + threadIdx.x;
    if (i < M) out[i] += bsum[blockIdx.x];
}

// ---- phase 3: scatter edges into bucket-partitioned pair array ----
__global__ void k_part(const int* __restrict__ row, const int* __restrict__ col,
                       const int* __restrict__ hscan, int2* __restrict__ pairs,
                       int E, int nbuk, int chunk) {
    __shared__ int cur[NBUK_MAX];
    int b = blockIdx.x;
    for (int i = threadIdx.x; i < nbuk; i += 256) cur[i] = hscan[i * PB + b];
    __syncthreads();
    int lo = b * chunk, hi = min(E, lo + chunk);
    for (int e = lo + threadIdx.x; e < hi; e += 256) {
        int c = col[e];
        int r = row[e];
        int pos = atomicAdd(&cur[c >> NRSH], 1);
        pairs[pos] = make_int2(c, r);
    }
}

// ---- phase 4: one block per bucket: LDS deg-hist -> scan -> startv/deg/cnt -> fill ----
__global__ __launch_bounds__(256) void k_fillb(const int2* __restrict__ pairs,
        const int* __restrict__ hscan, int* __restrict__ csr,
        int* __restrict__ startv, int* __restrict__ deg, float* __restrict__ cnt,
        int E, int N, int nbuk) {
    __shared__ int dh[512];
    __shared__ int sc[256];
    int b = blockIdx.x;
    int tid = threadIdx.x;
    int nlo = b << NRSH;
    int s0 = hscan[b * PB];
    int e0 = (b == nbuk - 1) ? E : hscan[(b + 1) * PB];
    dh[tid] = 0; dh[tid + 256] = 0;
    __syncthreads();
    for (int i = s0 + tid; i < e0; i += 256)
        atomicAdd(&dh[pairs[i].x - nlo], 1);
    __syncthreads();
    int v0 = dh[2 * tid], v1 = dh[2 * tid + 1];
    int ps = v0 + v1;
    sc[tid] = ps;
    __syncthreads();
    int acc = ps;
    for (int off = 1; off < 256; off <<= 1) {
        int t = (tid >= off) ? sc[tid - off] : 0;
        __syncthreads();
        acc += t;
        sc[tid] = acc;
        __syncthreads();
    }
    int excl = acc - ps;
    int o0 = excl, o1 = excl + v0;
    int n0 = nlo + 2 * tid, n1 = n0 + 1;
    if (n0 < N) { startv[n0] = s0 + o0; deg[n0] = v0; cnt[n0] = (float)v0; }
    if (n1 < N) { startv[n1] = s0 + o1; deg[n1] = v1; cnt[n1] = (float)v1; }
    __syncthreads();
    dh[2 * tid] = o0;
    dh[2 * tid + 1] = o1;
    __syncthreads();
    for (int i = s0 + tid; i < e0; i += 256) {
        int2 p = pairs[i];
        int pos = atomicAdd(&dh[p.x - nlo], 1);
        csr[s0 + pos] = p.y;
    }
}

// ---- pack W [128][64] fp32 -> MFMA B-fragments fp16 ----
__global__ void k_packW(const float* __restrict__ msgW, const float* __restrict__ updW,
                        _Float16* __restrict__ wpk) {
    int mat = blockIdx.x;
    const float* W = (mat < 2) ? (msgW + (size_t)mat * 2 * H * H)
                               : (updW + (size_t)(mat - 2) * 2 * H * H);
    _Float16* dst = wpk + (size_t)mat * 16 * 64 * 8;
    for (int e = threadIdx.x; e < 16 * 64; e += 256) {
        int fidx = e >> 6;
        int l = e & 63;
        int hf = fidx >> 3;
        int s = (fidx >> 2) & 1;
        int t = fidx & 3;
        int kbase = hf * 64 + s * 32 + ((l >> 4) * 8);
        int c = t * 16 + (l & 15);
        _Float16* d = dst + (size_t)e * 8;
        #pragma unroll
        for (int i = 0; i < 8; ++i)
            d[i] = (_Float16)W[(size_t)(kbase + i) * H + c];
    }
}

// ---- h16 = fp16(x @ W_in + b_in) ----
__global__ void k_input(const float* __restrict__ x, const float* __restrict__ Win,
                        const float* __restrict__ bin, _Float16* __restrict__ h16, int N) {
    __shared__ float w[FIN * H];
    int tid = threadIdx.x;
    for (int i = tid; i < FIN * H; i += 512) w[i] = Win[i];
    __syncthreads();
    int j = tid & 63;
    int un = __builtin_amdgcn_readfirstlane(blockIdx.x * 32 + (tid >> 6) * 4);
    int n0 = min(un, N - 1), n1 = min(un + 1, N - 1), n2 = min(un + 2, N - 1), n3 = min(un + 3, N - 1);
    const float* x0 = x + (size_t)n0 * FIN;
    const float* x1 = x + (size_t)n1 * FIN;
    const float* x2 = x + (size_t)n2 * FIN;
    const float* x3 = x + (size_t)n3 * FIN;
    float a0 = 0.f, a1 = 0.f, a2 = 0.f, a3 = 0.f;
    #pragma unroll
    for (int k = 0; k < FIN; ++k) {
        float wv = w[k * H + j];
        a0 += x0[k] * wv;
        a1 += x1[k] * wv;
        a2 += x2[k] * wv;
        a3 += x3[k] * wv;
    }
    float bj = bin[j];
    if (un     < N) h16[(size_t)n0 * H + j] = (_Float16)(a0 + bj);
    if (un + 1 < N) h16[(size_t)n1 * H + j] = (_Float16)(a1 + bj);
    if (un + 2 < N) h16[(size_t)n2 * H + j] = (_Float16)(a2 + bj);
    if (un + 3 < N) h16[(size_t)n3 * H + j] = (_Float16)(a3 + bj);
}

// ---- MFMA: A(fp16) = h@W_top ; aggr_init = cnt*(h@W_bot + msg_b) ----
__global__ __launch_bounds__(256) void k_AB(const _Float16* __restrict__ h16,
        const _Float16* __restrict__ wpk, const float* __restrict__ bias,
        const float* __restrict__ cnt, _Float16* __restrict__ A,
        float* __restrict__ ag, int N) {
    int l = threadIdx.x & 63;
    int w = threadIdx.x >> 6;
    int n0 = blockIdx.x * 64 + w * 16;
    int mrow = l & 15, kgrp = l >> 4;
    int nA = min(n0 + mrow, N - 1);
    half8 ah0 = *(const half8*)(h16 + (size_t)nA * H + kgrp * 8);
    half8 ah1 = *(const half8*)(h16 + (size_t)nA * H + 32 + kgrp * 8);
    floatx4 accA[4] = {};
    floatx4 accB[4] = {};
    #pragma unroll
    for (int s = 0; s < 2; ++s) {
        half8 a = s ? ah1 : ah0;
        #pragma unroll
        for (int t = 0; t < 4; ++t) {
            half8 bt = *(const half8*)(wpk + ((size_t)((s * 4 + t) * 64 + l)) * 8);
            half8 bb = *(const half8*)(wpk + ((size_t)((8 + s * 4 + t) * 64 + l)) * 8);
            accA[t] = __builtin_amdgcn_mfma_f32_16x16x32_f16(a, bt, accA[t], 0, 0, 0);
            accB[t] = __builtin_amdgcn_mfma_f32_16x16x32_f16(a, bb, accB[t], 0, 0, 0);
        }
    }
    float bl[4];
    #pragma unroll
    for (int t = 0; t < 4; ++t) bl[t] = bias[t * 16 + mrow];
    #pragma unroll
    for (int r = 0; r < 4; ++r) {
        int n = n0 + kgrp * 4 + r;
        if (n < N) {
            float c = cnt[n];
            #pragma unroll
            for (int t = 0; t < 4; ++t) {
                int j = t * 16 + mrow;
                A[(size_t)n * H + j] = (_Float16)accA[t][r];
                ag[(size_t)n * H + j] = c * (accB[t][r] + bl[t]);
            }
        }
    }
}

// ---- aggr gather: 4 edges per wave-instruction, half4 row slices ----
__global__ void k_aggr(const int* __restrict__ startv, const int* __restrict__ deg,
                       const int* __restrict__ csr, const _Float16* __restrict__ A,
                       float* __restrict__ ag, int N) {
    int tid = threadIdx.x;
    int n = __builtin_amdgcn_readfirstlane(blockIdx.x * 4 + (tid >> 6));
    if (n >= N) return;
    int l = tid & 63;
    int q = l >> 4;
    int m = l & 15;
    int s = startv[n];
    int d = deg[n];
    float a0 = 0.f, a1 = 0.f, a2 = 0.f, a3 = 0.f;
    int i = 0;
    for (; i + 8 <= d; i += 8) {
        int rA = csr[s + i + q];
        int rB = csr[s + i + 4 + q];
        half4 hA = *(const half4*)(A + (size_t)rA * H + m * 4);
        half4 hB = *(const half4*)(A + (size_t)rB * H + m * 4);
        a0 += (float)hA[0] + (float)hB[0];
        a1 += (float)hA[1] + (float)hB[1];
        a2 += (float)hA[2] + (float)hB[2];
        a3 += (float)hA[3] + (float)hB[3];
    }
    for (; i < d; i += 4) {
        int ii = i + q;
        if (ii < d) {
            int r = csr[s + ii];
            half4 hv = *(const half4*)(A + (size_t)r * H + m * 4);
            a0 += (float)hv[0];
            a1 += (float)hv[1];
            a2 += (float)hv[2];
            a3 += (float)hv[3];
        }
    }
    a0 += __shfl_xor(a0, 16); a0 += __shfl_xor(a0, 32);
    a1 += __shfl_xor(a1, 16); a1 += __shfl_xor(a1, 32);
    a2 += __shfl_xor(a2, 16); a2 += __shfl_xor(a2, 32);
    a3 += __shfl_xor(a3, 16); a3 += __shfl_xor(a3, 32);
    if (q == 0) {
        float* p = ag + (size_t)n * H + m * 4;
        float4 base = *(const float4*)p;
        base.x += a0; base.y += a1; base.z += a2; base.w += a3;
        *(float4*)p = base;
    }
}

// ---- MFMA upd + LN (+ fused out MLP) ----
template<bool DO_OUT>
__global__ __launch_bounds__(256) void k_upd(const _Float16* __restrict__ h16in,
        const float* __restrict__ ag, const float* __restrict__ cnt,
        const _Float16* __restrict__ wpk, const float* __restrict__ bias,
        const float* __restrict__ lng, const float* __restrict__ lnb,
        _Float16* __restrict__ h16out,
        const float* __restrict__ W1, const float* __restrict__ b1,
        const float* __restrict__ W2, const float* __restrict__ b2,
        float* __restrict__ out, int N) {
    __shared__ float w1s[DO_OUT ? H * 32 : 1];
    __shared__ float hsmem[DO_OUT ? 4 * 16 * H : 1];
    if (DO_OUT) {
        for (int i = threadIdx.x; i < H * 32; i += 256) w1s[i] = W1[i];
    }
    int l = threadIdx.x & 63;
    int w = threadIdx.x >> 6;
    int n0 = blockIdx.x * 64 + w * 16;
    int mrow = l & 15, kgrp = l >> 4;
    int nA = min(n0 + mrow, N - 1);
    half8 ah0 = *(const half8*)(h16in + (size_t)nA * H + kgrp * 8);
    half8 ah1 = *(const half8*)(h16in + (size_t)nA * H + 32 + kgrp * 8);
    float rd = 1.0f / fmaxf(cnt[nA], 1.0f);
    half8 agf[2];
    #pragma unroll
    for (int s = 0; s < 2; ++s) {
        const float* gp = ag + (size_t)nA * H + s * 32 + kgrp * 8;
        float4 g0 = *(const float4*)gp;
        float4 g1 = *(const float4*)(gp + 4);
        half8 v;
        v[0] = (_Float16)(g0.x * rd); v[1] = (_Float16)(g0.y * rd);
        v[2] = (_Float16)(g0.z * rd); v[3] = (_Float16)(g0.w * rd);
        v[4] = (_Float16)(g1.x * rd); v[5] = (_Float16)(g1.y * rd);
        v[6] = (_Float16)(g1.z * rd); v[7] = (_Float16)(g1.w * rd);
        agf[s] = v;
    }
    floatx4 acc[4] = {};
    #pragma unroll
    for (int s = 0; s < 2; ++s) {
        half8 a = s ? ah1 : ah0;
        half8 gfr = agf[s];
        #pragma unroll
        for (int t = 0; t < 4; ++t) {
            half8 bt = *(const half8*)(wpk + ((size_t)((s * 4 + t) * 64 + l)) * 8);
            half8 bb = *(const half8*)(wpk + ((size_t)((8 + s * 4 + t) * 64 + l)) * 8);
            acc[t] = __builtin_amdgcn_mfma_f32_16x16x32_f16(a, bt, acc[t], 0, 0, 0);
            acc[t] = __builtin_amdgcn_mfma_f32_16x16x32_f16(gfr, bb, acc[t], 0, 0, 0);
        }
    }
    float bl[4], gl[4], bb2[4];
    #pragma unroll
    for (int t = 0; t < 4; ++t) {
        int j = t * 16 + mrow;
        bl[t] = bias[j]; gl[t] = lng[j]; bb2[t] = lnb[j];
    }
    float zt[4][4];
    #pragma unroll
    for (int r = 0; r < 4; ++r) {
        int n = min(n0 + kgrp * 4 + r, N - 1);
        #pragma unroll
        for (int t = 0; t < 4; ++t) {
            float hv = (float)h16in[(size_t)n * H + t * 16 + mrow];
            zt[t][r] = hv + acc[t][r] + bl[t];
        }
    }
    #pragma unroll
    for (int r = 0; r < 4; ++r) {
        float s = zt[0][r] + zt[1][r] + zt[2][r] + zt[3][r];
        s += __shfl_xor(s, 1); s += __shfl_xor(s, 2);
        s += __shfl_xor(s, 4); s += __shfl_xor(s, 8);
        float mu = s * (1.0f / H);
        float v = 0.f;
        #pragma unroll
        for (int t = 0; t < 4; ++t) { float d = zt[t][r] - mu; v += d * d; }
        v += __shfl_xor(v, 1); v += __shfl_xor(v, 2);
        v += __shfl_xor(v, 4); v += __shfl_xor(v, 8);
        float rinv = rsqrtf(v * (1.0f / H) + 1e-5f);
        int m = kgrp * 4 + r;
        int n = n0 + m;
        #pragma unroll
        for (int t = 0; t < 4; ++t) {
            float hval = (zt[t][r] - mu) * rinv * gl[t] + bb2[t];
            if (DO_OUT) hsmem[(w * 16 + m) * H + t * 16 + mrow] = hval;
            else if (n < N) h16out[(size_t)n * H + t * 16 + mrow] = (_Float16)hval;
        }
    }
    if (DO_OUT) {
        __syncthreads();
        int hf = l >> 5, jj = l & 31;
        float w2v = W2[jj];
        float b1v = b1[jj];
        float b2v = b2[0];
        for (int nn = 0; nn < 16; ++nn) {
            int n = n0 + nn;
            if (n >= N) continue;
            const float* hrow = &hsmem[(w * 16 + nn) * H];
            float t = 0.f;
            #pragma unroll
            for (int kk = 0; kk < 32; ++kk)
                t += hrow[hf * 32 + kk] * w1s[(hf * 32 + kk) * 32 + jj];
            t += __shfl_xor(t, 32);
            float t2 = t + b1v;
            float ge = 0.5f * t2 * (1.0f + erff(t2 * 0.70710678118654752f)) * w2v;
            ge += __shfl_xor(ge, 16); ge += __shfl_xor(ge, 8);
            ge += __shfl_xor(ge, 4);  ge += __shfl_xor(ge, 2);
            ge += __shfl_xor(ge, 1);
            if (l == 0) out[n] = 1.0f / (1.0f + expf(-(ge + b2v)));
        }
    }
}

extern "C" void kernel_launch(void* const* d_in, const int* in_sizes, int n_in,
                              void* d_out, int out_size, void* d_ws, size_t ws_size,
                              hipStream_t stream) {
    const float* x    = (const float*)d_in[0];
    const int*   ei   = (const int*)d_in[1];
    const float* Win  = (const float*)d_in[2];
    const float* bin  = (const float*)d_in[3];
    const float* msgW = (const float*)d_in[4];
    const float* msgb = (const float*)d_in[5];
    const float* updW = (const float*)d_in[6];
    const float* updb = (const float*)d_in[7];
    const float* lng  = (const float*)d_in[8];
    const float* lnb  = (const float*)d_in[9];
    const float* W1   = (const float*)d_in[10];
    const float* b1   = (const float*)d_in[11];
    const float* W2   = (const float*)d_in[12];
    const float* b2   = (const float*)d_in[13];

    int N = in_sizes[0] / FIN;
    int E = in_sizes[1] / 2;
    const int* row = ei;
    const int* col = ei + E;

    int nbuk = (N + 511) >> NRSH;         // 196 for N=100000
    int M = nbuk * PB;                    // histogram size
    int chunk = (E + PB - 1) / PB;

    float* wsp  = (float*)d_ws;
    float* cnt  = wsp;                           // N f32
    float* Z    = wsp + N;                       // N*H f32 (aggr)
    _Float16* Ah   = (_Float16*)(Z + (size_t)N * H);   // N*H f16
    _Float16* h16a = Ah + (size_t)N * H;         // N*H f16
    _Float16* h16b = h16a + (size_t)N * H;       // N*H f16
    _Float16* wpk  = h16b + (size_t)N * H;       // 64KB
    int* deg    = (int*)(wpk + 4 * 16 * 64 * 8); // N
    int* startv = deg + N;                       // N
    int* bsum   = startv + N;                    // 512
    int* hist   = bsum + 512;                    // M
    int* hscan  = hist + M;                      // M
    int* csr    = hscan + M;                     // E
    uintptr_t pa = (uintptr_t)(csr + E);
    pa = (pa + 7) & ~(uintptr_t)7;
    int2* pairs = (int2*)pa;                     // E int2

    int nb64 = (N + 63) / 64;
    int scanblk = (M + 255) / 256;               // 392 <= 512

    k_packW<<<4, 256, 0, stream>>>(msgW, updW, wpk);

    // two-level radix CSR build: bucket (512 nodes) partition, then per-bucket fill
    k_hist<<<PB, 256, 0, stream>>>(col, hist, E, nbuk, chunk);
    k_scanA<<<scanblk, 256, 0, stream>>>(hist, hscan, bsum, M);
    k_scan2<<<1, 512, 0, stream>>>(bsum, scanblk);
    k_scanC<<<scanblk, 256, 0, stream>>>(hscan, bsum, M);
    k_part<<<PB, 256, 0, stream>>>(row, col, hscan, pairs, E, nbuk, chunk);
    k_fillb<<<nbuk, 256, 0, stream>>>(pairs, hscan, csr, startv, deg, cnt, E, N, nbuk);

    k_input<<<(N + 31) / 32, 512, 0, stream>>>(x, Win, bin, h16a, N);

    // layer 0: h=h16a -> A->Ah, aggr->Z, hout->h16b
    k_AB<<<nb64, 256, 0, stream>>>(h16a, wpk + 0 * 8192, msgb, cnt, Ah, Z, N);
    k_aggr<<<(N + 3) / 4, 256, 0, stream>>>(startv, deg, csr, Ah, Z, N);
    k_upd<false><<<nb64, 256, 0, stream>>>(h16a, Z, cnt, wpk + 2 * 8192, updb, lng, lnb,
                                           h16b, nullptr, nullptr, nullptr, nullptr,
                                           nullptr, N);

    // layer 1: h=h16b -> A->Ah, aggr->Z, fused final MLP -> d_out
    k_AB<<<nb64, 256, 0, stream>>>(h16b, wpk + 1 * 8192, msgb + H, cnt, Ah, Z, N);
    k_aggr<<<(N + 3) / 4, 256, 0, stream>>>(startv, deg, csr, Ah, Z, N);
    k_upd<true><<<nb64, 256, 0, stream>>>(h16b, Z, cnt, wpk + 3 * 8192, updb + H,
                                          lng + H, lnb + H, nullptr,
                                          W1, b1, W2, b2, (float*)d_out, N);
}